// Round 6
// baseline (462.202 us; speedup 1.0000x reference)
//
#include <hip/hip_runtime.h>
#include <stdint.h>
#include <stddef.h>

#define D0 4096
#define D1 1024
#define NOUT 1000
#define NB 64

// ---------------------------------------------------------------------------
// Compile-time fp32-faithful spike pattern, N in [0,32] -> 32-bit cycle mask.
// Replicates runtime fp32 semantics EXACTLY: spacing = fl32(32/N), spike at c
// iff fmodf(c, spacing) < 1.  fmodf is exact: r = c - trunc(c/sp)*sp with the
// product/difference exact in double (<= 29+6 significant bits).  The double
// quotient's rounding (2^-48) cannot cross an integer boundary because the
// true quotient is either exactly integral or >= 2^-28 away from one.
// NOTE: the "ideal" integer pattern ((c*N)&31)<N is NOT equivalent (e.g.
// N=24,c=4: fp32 says no spike, integer says spike) — must replicate fp32.
// ---------------------------------------------------------------------------
constexpr uint32_t spike_pattern_ct(int N) {
  if (N <= 0) return 0u;
  if (N >= 32) return 0xFFFFFFFFu;
  float sp = 32.0f / (float)N;
  uint32_t m = 0;
  for (int c = 0; c < 32; ++c) {
    double q = (double)c / (double)sp;
    int n = (int)q;                       // trunc, q >= 0
    double r = (double)c - (double)n * (double)sp;   // == fmodf(c, sp), exact
    if (r < 1.0) m |= (1u << c);
  }
  return m;
}

// ---------------------------------------------------------------------------
// Transpose w0 (4096x4096) -> w0T[j][o].  float4 on both global sides.
// ---------------------------------------------------------------------------
__global__ void transpose_w0_k(const float* __restrict__ w, float* __restrict__ wt) {
  __shared__ float tile[32][33];
  int j0 = blockIdx.x * 32;
  int o0 = blockIdx.y * 32;
  int tx = threadIdx.x, ty = threadIdx.y;
  float4 v = *reinterpret_cast<const float4*>(&w[(size_t)(o0 + ty) * D0 + j0 + 4 * tx]);
  tile[ty][4 * tx + 0] = v.x;
  tile[ty][4 * tx + 1] = v.y;
  tile[ty][4 * tx + 2] = v.z;
  tile[ty][4 * tx + 3] = v.w;
  __syncthreads();
  float4 u;
  u.x = tile[4 * tx + 0][ty];
  u.y = tile[4 * tx + 1][ty];
  u.z = tile[4 * tx + 2][ty];
  u.w = tile[4 * tx + 3][ty];
  *reinterpret_cast<float4*>(&wt[(size_t)(j0 + ty) * D0 + o0 + 4 * tx]) = u;
}

// Transpose w2 (1000x1024) -> w2T[j][o], o padded to 1024 with zeros.
__global__ void transpose_w2_k(const float* __restrict__ w, float* __restrict__ wt) {
  __shared__ float tile[32][33];
  int j0 = blockIdx.x * 32;
  int o0 = blockIdx.y * 32;
  int tx = threadIdx.x, ty = threadIdx.y;
  int o = o0 + ty;
  float4 v = make_float4(0.f, 0.f, 0.f, 0.f);
  if (o < NOUT) v = *reinterpret_cast<const float4*>(&w[(size_t)o * D1 + j0 + 4 * tx]);
  tile[ty][4 * tx + 0] = v.x;
  tile[ty][4 * tx + 1] = v.y;
  tile[ty][4 * tx + 2] = v.z;
  tile[ty][4 * tx + 3] = v.w;
  __syncthreads();
  float4 u;
  u.x = tile[4 * tx + 0][ty];
  u.y = tile[4 * tx + 1][ty];
  u.z = tile[4 * tx + 2][ty];
  u.w = tile[4 * tx + 3][ty];
  *reinterpret_cast<float4*>(&wt[(size_t)(j0 + ty) * D1 + o0 + 4 * tx]) = u;
}

// ---------------------------------------------------------------------------
// N0(b,d) = round_half_even(x * 32)   (matches jnp.round in fp32)
// ---------------------------------------------------------------------------
__global__ void compute_N0_k(const float* __restrict__ x, int* __restrict__ N0) {
  int i = blockIdx.x * 256 + threadIdx.x;
  N0[i] = (int)rintf(x[i] * 32.0f);
}

// ---------------------------------------------------------------------------
// Per-batch counting sort of D inputs by key = Nsrc[b][idx[j]] (33 keys).
// perm[b][pos] = j, sorted ascending by key; starts[b][k] = bucket k begin.
// Order within a key is non-deterministic (atomics) — only perturbs fp64
// bucket-sum rounding at ~1e-16, irrelevant vs threshold margins.
// ---------------------------------------------------------------------------
template <int D>
__global__ void prep_sort_k(const int* __restrict__ Nsrc, const int* __restrict__ idx,
                            uint32_t* __restrict__ perm, int* __restrict__ starts) {
  __shared__ int keys[D];
  __shared__ int hist[33];
  __shared__ int base[34];
  __shared__ int cursor[33];
  int b = blockIdx.x;
  int tid = threadIdx.x;
  if (tid < 33) hist[tid] = 0;
  __syncthreads();
  for (int j = tid; j < D; j += 256) {
    int k = Nsrc[b * D + idx[j]];
    keys[j] = k;
    atomicAdd(&hist[k], 1);
  }
  __syncthreads();
  if (tid == 0) {
    int s = 0;
    for (int k = 0; k < 33; ++k) { base[k] = s; cursor[k] = s; s += hist[k]; }
    base[33] = s;
  }
  __syncthreads();
  if (tid < 34) starts[b * 34 + tid] = base[tid];
  for (int j = tid; j < D; j += 256) {
    int k = keys[j];
    int pos = atomicAdd(&cursor[k], 1);
    perm[b * D + pos] = (uint32_t)j;
  }
}

// ---------------------------------------------------------------------------
// LIF core, bucket decomposition, fp64-exact.
//
// Round-5 structure retained (L2-resident o-stripe per XCD, j-split across
// block halves, scalarized perm/bounds, bucket-sum LDS combine, compile-time
// -mask membrane scan).
//
// Round-6 change: attack the remaining LATENCY coupling (280us vs 125us L2
// floor at 45% L2-BW / 34% VALU — neither pipe saturated):
//  * 16-wide groups with SOFTWARE-PIPELINED perm prefetch: the next group's
//    perm s_loads issue while the current group's 16 gathers are in flight,
//    removing the serial {perm wait -> gather wait} chain.  In-flight bytes:
//    16 loads x 256 B x 16 waves = 64 KB/CU >> 16.8 KB latency-BW product.
//  * Branchless masked TAIL batch (<=15 elems): clamped scalar index + zero
//    select.  All tail loads issue concurrently with ONE wait — round-5 paid
//    up to 7 serial ~400cy round-trips per segment tail (segments avg ~62/half,
//    so tails were a first-order term, not an edge case).
// ---------------------------------------------------------------------------
template <int D, int OSTRIDE, int TILES>
__launch_bounds__(512, 4)
__global__ void lif_core_k(const float* __restrict__ wt, const uint32_t* __restrict__ perm,
                           const int* __restrict__ starts, const float* __restrict__ thr_p,
                           int* __restrict__ cnt_out) {
  __shared__ double cshare[16][256];   // 32 KB: bucket-sum exchange, 2 chunks
  int tid = threadIdx.x;
  int b = blockIdx.y;
  int col = tid & 255;
  int half = __builtin_amdgcn_readfirstlane(tid >> 8);  // SGPR: waves 0-3 -> 0, 4-7 -> 1

  const uint32_t* permb = perm + (size_t)b * D;
  const int* st = starts + b * 34;
  double th = (double)thr_p[0];

  for (int zt = 0; zt < TILES; ++zt) {
    int o = (blockIdx.x + gridDim.x * zt) * 256 + col;

    double bs[33];
#pragma unroll
    for (int k = 1; k <= 32; ++k) bs[k] = 0.0;

#pragma unroll
    for (int k = 1; k <= 32; ++k) {    // k=0: empty pattern, segment skipped
      int s = __builtin_amdgcn_readfirstlane(st[k]);
      int e = __builtin_amdgcn_readfirstlane(st[k + 1]);
      if (s == e) continue;            // scalar branch
      int mid = s + ((e - s) >> 1);
      int i  = half ? mid : s;         // SGPR cselect
      int i1 = half ? e : mid;
      double a0 = 0.0, a1 = 0.0, a2 = 0.0, a3 = 0.0;

      // ---- 16-wide pipelined main loop: perm(next) overlaps gathers(cur) ----
      if (i + 16 <= i1) {
        int jc[16];
#pragma unroll
        for (int u = 0; u < 16; ++u)
          jc[u] = __builtin_amdgcn_readfirstlane((int)permb[i + u]);
        i += 16;
        for (;;) {
          float f[16];
#pragma unroll
          for (int u = 0; u < 16; ++u)
            f[u] = wt[(size_t)(uint32_t)jc[u] * OSTRIDE + o];  // issue 16 gathers
          bool more = (i + 16 <= i1);                          // scalar
          if (more) {
#pragma unroll
            for (int u = 0; u < 16; ++u)                       // prefetch next perm
              jc[u] = __builtin_amdgcn_readfirstlane((int)permb[i + u]);
            i += 16;
          }
#pragma unroll
          for (int u = 0; u < 16; u += 4) {                    // vmcnt-staged waits
            a0 += (double)f[u + 0];
            a1 += (double)f[u + 1];
            a2 += (double)f[u + 2];
            a3 += (double)f[u + 3];
          }
          if (!more) break;
        }
      }

      // ---- branchless masked tail (1..15 elems): one concurrent batch ----
      if (i < i1) {
        int rem = i1 - i;              // scalar, 1..15
        float ft[15];
#pragma unroll
        for (int u = 0; u < 15; ++u) {
          int idx = i + u;
          if (idx > i1 - 1) idx = i1 - 1;                      // scalar clamp
          int j = __builtin_amdgcn_readfirstlane((int)permb[idx]);
          ft[u] = wt[(size_t)(uint32_t)j * OSTRIDE + o];
        }
#pragma unroll
        for (int u = 0; u < 15; ++u) {
          float fz = (u < rem) ? ft[u] : 0.0f;                 // zero masked slots
          double d = (double)fz;
          if ((u & 3) == 0) a0 += d;
          else if ((u & 3) == 1) a1 += d;
          else if ((u & 3) == 2) a2 += d;
          else a3 += d;
        }
      }

      bs[k] = (a0 + a1) + (a2 + a3);
    }

    // Combine halves at bucket-sum level (2 chunks of 16 through 32 KB LDS).
    __syncthreads();                   // also guards cshare reuse across zt
    if (half) {
#pragma unroll
      for (int k = 1; k <= 16; ++k) cshare[k - 1][col] = bs[k];
    }
    __syncthreads();
    if (!half) {
#pragma unroll
      for (int k = 1; k <= 16; ++k) bs[k] += cshare[k - 1][col];
    }
    __syncthreads();
    if (half) {
#pragma unroll
      for (int k = 17; k <= 32; ++k) cshare[k - 17][col] = bs[k];
    }
    __syncthreads();
    if (!half) {
#pragma unroll
      for (int k = 17; k <= 32; ++k) bs[k] += cshare[k - 17][col];

      // Membrane scan: 528 compile-time-selected fp64 adds, no masks.
      double memb = 0.0;
      int cnt = 0;
#pragma unroll
      for (int t = 0; t < 32; ++t) {
#pragma unroll
        for (int k = 1; k <= 32; ++k)
          if ((spike_pattern_ct(k) >> t) & 1u) memb += bs[k];
        if (memb > th) { memb -= th; ++cnt; }   // strict: threshold < memb
      }
      cnt_out[(size_t)b * OSTRIDE + o] = cnt;
    }
  }
}

// ---------------------------------------------------------------------------
// avg_pool2d on exact spike counts + re-encode: N1 = round_half_even(count4/4)
// ---------------------------------------------------------------------------
__global__ void pool_encode_k(const int* __restrict__ k0, const int* __restrict__ idx1,
                              int* __restrict__ N1) {
  int i = blockIdx.x * 256 + threadIdx.x;  // 64*1024
  int b = i >> 10;
  int q2 = i & 1023;
  int c = q2 >> 4;
  int h2 = (q2 >> 2) & 3;
  int w2 = q2 & 3;
  int cnt = 0;
#pragma unroll
  for (int dh = 0; dh < 2; ++dh)
#pragma unroll
    for (int dw = 0; dw < 2; ++dw) {
      int q = c * 64 + (2 * h2 + dh) * 8 + (2 * w2 + dw);
      cnt += k0[b * D0 + idx1[q]];
    }
  N1[i] = (int)rintf((float)cnt * 0.25f);
}

__global__ void write_out_k(const int* __restrict__ cnt2, const int* __restrict__ idx_out,
                            float* __restrict__ out) {
  int i = blockIdx.x * 256 + threadIdx.x;
  if (i >= NB * NOUT) return;
  int b = i / NOUT;
  int r = i - b * NOUT;
  out[i] = (float)cnt2[b * D1 + idx_out[r]];
}

// ---------------------------------------------------------------------------
extern "C" void kernel_launch(void* const* d_in, const int* in_sizes, int n_in,
                              void* d_out, int out_size, void* d_ws, size_t ws_size,
                              hipStream_t stream) {
  const float* x      = (const float*)d_in[0];
  const float* w0     = (const float*)d_in[1];
  const float* t0     = (const float*)d_in[2];
  const float* w2     = (const float*)d_in[3];
  const float* t2     = (const float*)d_in[4];
  const int*   idx0   = (const int*)d_in[5];
  const int*   idx1   = (const int*)d_in[6];
  const int*   idx2   = (const int*)d_in[7];
  const int*   idx_out= (const int*)d_in[8];
  float* out = (float*)d_out;

  char* ws = (char*)d_ws;
  float*    w0T    = (float*)ws;    ws += (size_t)D0 * D0 * 4;   // 64 MB
  float*    w2T    = (float*)ws;    ws += (size_t)D1 * D1 * 4;   // 4 MB
  uint32_t* perm0  = (uint32_t*)ws; ws += (size_t)NB * D0 * 4;
  uint32_t* perm2  = (uint32_t*)ws; ws += (size_t)NB * D1 * 4;
  int*      N0     = (int*)ws;      ws += (size_t)NB * D0 * 4;
  int*      N1     = (int*)ws;      ws += (size_t)NB * D1 * 4;
  int*      k0     = (int*)ws;      ws += (size_t)NB * D0 * 4;
  int*      cnt2   = (int*)ws;      ws += (size_t)NB * D1 * 4;
  int*      starts0= (int*)ws;      ws += (size_t)NB * 34 * 4;
  int*      starts2= (int*)ws;      ws += (size_t)NB * 34 * 4;

  transpose_w0_k<<<dim3(D0 / 32, D0 / 32), dim3(8, 32), 0, stream>>>(w0, w0T);
  transpose_w2_k<<<dim3(D1 / 32, D1 / 32), dim3(8, 32), 0, stream>>>(w2, w2T);
  compute_N0_k<<<NB * D0 / 256, 256, 0, stream>>>(x, N0);
  prep_sort_k<D0><<<NB, 256, 0, stream>>>(N0, idx0, perm0, starts0);
  // 512 blocks x 512 thr = 2 blocks/CU = 16 waves/CU; XCD x holds ONE 4 MB
  // o-stripe at a time (tiles x, then x+8 via zt loop).
  lif_core_k<D0, D0, 2><<<dim3(8, NB, 1), 512, 0, stream>>>(w0T, perm0, starts0, t0, k0);
  pool_encode_k<<<NB * D1 / 256, 256, 0, stream>>>(k0, idx1, N1);
  prep_sort_k<D1><<<NB, 256, 0, stream>>>(N1, idx2, perm2, starts2);
  lif_core_k<D1, D1, 1><<<dim3(4, NB, 1), 512, 0, stream>>>(w2T, perm2, starts2, t2, cnt2);
  write_out_k<<<(NB * NOUT + 255) / 256, 256, 0, stream>>>(cnt2, idx_out, out);
}

// Round 7
// 432.636 us; speedup vs baseline: 1.0683x; 1.0683x over previous
//
#include <hip/hip_runtime.h>
#include <stdint.h>
#include <stddef.h>

#define D0 4096
#define D1 1024
#define NOUT 1000
#define NB 64

// ---------------------------------------------------------------------------
// Compile-time fp32-faithful spike pattern, N in [0,32] -> 32-bit cycle mask.
// Replicates runtime fp32 semantics EXACTLY: spacing = fl32(32/N), spike at c
// iff fmodf(c, spacing) < 1.  fmodf is exact: r = c - trunc(c/sp)*sp with the
// product/difference exact in double (<= 29+6 significant bits).  The double
// quotient's rounding (2^-48) cannot cross an integer boundary because the
// true quotient is either exactly integral or >= 2^-28 away from one.
// NOTE: the "ideal" integer pattern ((c*N)&31)<N is NOT equivalent (e.g.
// N=24,c=4: fp32 says no spike, integer says spike) — must replicate fp32.
// ---------------------------------------------------------------------------
constexpr uint32_t spike_pattern_ct(int N) {
  if (N <= 0) return 0u;
  if (N >= 32) return 0xFFFFFFFFu;
  float sp = 32.0f / (float)N;
  uint32_t m = 0;
  for (int c = 0; c < 32; ++c) {
    double q = (double)c / (double)sp;
    int n = (int)q;                       // trunc, q >= 0
    double r = (double)c - (double)n * (double)sp;   // == fmodf(c, sp), exact
    if (r < 1.0) m |= (1u << c);
  }
  return m;
}

// ---------------------------------------------------------------------------
// Transpose w0 (4096x4096) -> w0T[j][o].  float4 on both global sides.
// ---------------------------------------------------------------------------
__global__ void transpose_w0_k(const float* __restrict__ w, float* __restrict__ wt) {
  __shared__ float tile[32][33];
  int j0 = blockIdx.x * 32;
  int o0 = blockIdx.y * 32;
  int tx = threadIdx.x, ty = threadIdx.y;
  float4 v = *reinterpret_cast<const float4*>(&w[(size_t)(o0 + ty) * D0 + j0 + 4 * tx]);
  tile[ty][4 * tx + 0] = v.x;
  tile[ty][4 * tx + 1] = v.y;
  tile[ty][4 * tx + 2] = v.z;
  tile[ty][4 * tx + 3] = v.w;
  __syncthreads();
  float4 u;
  u.x = tile[4 * tx + 0][ty];
  u.y = tile[4 * tx + 1][ty];
  u.z = tile[4 * tx + 2][ty];
  u.w = tile[4 * tx + 3][ty];
  *reinterpret_cast<float4*>(&wt[(size_t)(j0 + ty) * D0 + o0 + 4 * tx]) = u;
}

// Transpose w2 (1000x1024) -> w2T[j][o], o padded to 1024 with zeros.
__global__ void transpose_w2_k(const float* __restrict__ w, float* __restrict__ wt) {
  __shared__ float tile[32][33];
  int j0 = blockIdx.x * 32;
  int o0 = blockIdx.y * 32;
  int tx = threadIdx.x, ty = threadIdx.y;
  int o = o0 + ty;
  float4 v = make_float4(0.f, 0.f, 0.f, 0.f);
  if (o < NOUT) v = *reinterpret_cast<const float4*>(&w[(size_t)o * D1 + j0 + 4 * tx]);
  tile[ty][4 * tx + 0] = v.x;
  tile[ty][4 * tx + 1] = v.y;
  tile[ty][4 * tx + 2] = v.z;
  tile[ty][4 * tx + 3] = v.w;
  __syncthreads();
  float4 u;
  u.x = tile[4 * tx + 0][ty];
  u.y = tile[4 * tx + 1][ty];
  u.z = tile[4 * tx + 2][ty];
  u.w = tile[4 * tx + 3][ty];
  *reinterpret_cast<float4*>(&wt[(size_t)(j0 + ty) * D1 + o0 + 4 * tx]) = u;
}

// ---------------------------------------------------------------------------
// Per-batch counting sort of D0 inputs by key = rint(x[b][idx0[j]]*32).
// (compute_N0 fused in — N0 buffer and its kernel launch eliminated.)
// perm[b][pos] = j (u16), ascending by key; starts[b][k] = bucket begin.
// Within-key order nondeterministic (atomics) — perturbs fp64 bucket-sum
// rounding at ~1e-16 only.
// ---------------------------------------------------------------------------
__global__ void prep_sort0_k(const float* __restrict__ x, const int* __restrict__ idx0,
                             uint16_t* __restrict__ perm, int* __restrict__ starts) {
  __shared__ int keys[D0];
  __shared__ int hist[33];
  __shared__ int base[34];
  __shared__ int cursor[33];
  int b = blockIdx.x;
  int tid = threadIdx.x;
  if (tid < 33) hist[tid] = 0;
  __syncthreads();
  for (int j = tid; j < D0; j += 256) {
    int k = (int)rintf(x[b * D0 + idx0[j]] * 32.0f);
    keys[j] = k;
    atomicAdd(&hist[k], 1);
  }
  __syncthreads();
  if (tid == 0) {
    int s = 0;
    for (int k = 0; k < 33; ++k) { base[k] = s; cursor[k] = s; s += hist[k]; }
    base[33] = s;
  }
  __syncthreads();
  if (tid < 34) starts[b * 34 + tid] = base[tid];
  for (int j = tid; j < D0; j += 256) {
    int k = keys[j];
    int pos = atomicAdd(&cursor[k], 1);
    perm[b * D0 + pos] = (uint16_t)j;
  }
}

// ---------------------------------------------------------------------------
// Per-batch counting sort of D1 inputs; key computed inline from spike counts:
//   q2 = idx2[j];  pooled count over the 2x2 window of channel-grid position
//   q2 via idx1 gather;  key = rint(count/4)  (pool_encode fused in — N1
//   buffer and kernel eliminated).  rates exact multiples of 1/128, clip no-op.
// ---------------------------------------------------------------------------
__global__ void prep_sort1_k(const int* __restrict__ k0, const int* __restrict__ idx1,
                             const int* __restrict__ idx2,
                             uint16_t* __restrict__ perm, int* __restrict__ starts) {
  __shared__ int keys[D1];
  __shared__ int hist[33];
  __shared__ int base[34];
  __shared__ int cursor[33];
  int b = blockIdx.x;
  int tid = threadIdx.x;
  if (tid < 33) hist[tid] = 0;
  __syncthreads();
  for (int j = tid; j < D1; j += 256) {
    int q2 = idx2[j];
    int c = q2 >> 4;
    int h2 = (q2 >> 2) & 3;
    int w2 = q2 & 3;
    int cnt = 0;
#pragma unroll
    for (int dh = 0; dh < 2; ++dh)
#pragma unroll
      for (int dw = 0; dw < 2; ++dw) {
        int q = c * 64 + (2 * h2 + dh) * 8 + (2 * w2 + dw);
        cnt += k0[b * D0 + idx1[q]];
      }
    int k = (int)rintf((float)cnt * 0.25f);
    keys[j] = k;
    atomicAdd(&hist[k], 1);
  }
  __syncthreads();
  if (tid == 0) {
    int s = 0;
    for (int k = 0; k < 33; ++k) { base[k] = s; cursor[k] = s; s += hist[k]; }
    base[33] = s;
  }
  __syncthreads();
  if (tid < 34) starts[b * 34 + tid] = base[tid];
  for (int j = tid; j < D1; j += 256) {
    int k = keys[j];
    int pos = atomicAdd(&cursor[k], 1);
    perm[b * D1 + pos] = (uint16_t)j;
  }
}

// ---------------------------------------------------------------------------
// LIF core, bucket decomposition, fp64-exact.
//
// Round-5 structure retained exactly (L2-resident o-stripe per XCD, j-split
// across block halves, scalarized bounds, 8-wide gather groups, bucket-sum
// LDS combine, compile-time-mask membrane scan).  Round-6's deeper pipeline
// + masked tail REGRESSED (FETCH 126->292 MB, +21us) — reverted.
//
// Round-7 change: perm lives in LDS (u16, staged once per block).  The
// per-group serial chain was {perm fetch via L2 (~200-400cy) -> issue 8
// gathers -> vmcnt(0) -> accumulate}; the perm leg becomes a ~60cy broadcast
// ds_read.  Side effect: perm leaves L2 entirely, so the XCD working set is
// the 4 MB w0T slice alone (was 5 MB marginal -> mild thrash, FETCH 2x ideal).
// ---------------------------------------------------------------------------
template <int D, int OSTRIDE, int TILES>
__launch_bounds__(512, 4)
__global__ void lif_core_k(const float* __restrict__ wt, const uint16_t* __restrict__ perm,
                           const int* __restrict__ starts, const float* __restrict__ thr_p,
                           int* __restrict__ cnt_out) {
  __shared__ double cshare[16][256];   // 32 KB: bucket-sum exchange, 2 chunks
  __shared__ uint16_t permS[D];        // 8 KB (D0) / 2 KB (D1)
  int tid = threadIdx.x;
  int b = blockIdx.y;
  int col = tid & 255;
  int half = __builtin_amdgcn_readfirstlane(tid >> 8);  // SGPR: waves 0-3 -> 0, 4-7 -> 1

  // Stage this batch's perm into LDS (coalesced ushort2).
  {
    const ushort2* p2 = reinterpret_cast<const ushort2*>(perm + (size_t)b * D);
    ushort2* s2 = reinterpret_cast<ushort2*>(permS);
    for (int i = tid; i < D / 2; i += 512) s2[i] = p2[i];
  }
  __syncthreads();

  const int* st = starts + b * 34;
  double th = (double)thr_p[0];

  for (int zt = 0; zt < TILES; ++zt) {
    int o = (blockIdx.x + gridDim.x * zt) * 256 + col;

    double bs[33];
#pragma unroll
    for (int k = 1; k <= 32; ++k) bs[k] = 0.0;

#pragma unroll
    for (int k = 1; k <= 32; ++k) {    // k=0: empty pattern, segment skipped
      int s = __builtin_amdgcn_readfirstlane(st[k]);
      int e = __builtin_amdgcn_readfirstlane(st[k + 1]);
      if (s == e) continue;            // scalar branch
      int mid = s + ((e - s) >> 1);
      int i  = half ? mid : s;         // SGPR cselect
      int i1 = half ? e : mid;
      double a0 = 0.0, a1 = 0.0, a2 = 0.0, a3 = 0.0;
      for (; i + 8 <= i1; i += 8) {    // scalar loop control
        int j0 = __builtin_amdgcn_readfirstlane((int)permS[i + 0]);
        int j1 = __builtin_amdgcn_readfirstlane((int)permS[i + 1]);
        int j2 = __builtin_amdgcn_readfirstlane((int)permS[i + 2]);
        int j3 = __builtin_amdgcn_readfirstlane((int)permS[i + 3]);
        int j4 = __builtin_amdgcn_readfirstlane((int)permS[i + 4]);
        int j5 = __builtin_amdgcn_readfirstlane((int)permS[i + 5]);
        int j6 = __builtin_amdgcn_readfirstlane((int)permS[i + 6]);
        int j7 = __builtin_amdgcn_readfirstlane((int)permS[i + 7]);
        float f0 = wt[(size_t)(uint32_t)j0 * OSTRIDE + o];   // saddr-form gathers
        float f1 = wt[(size_t)(uint32_t)j1 * OSTRIDE + o];
        float f2 = wt[(size_t)(uint32_t)j2 * OSTRIDE + o];
        float f3 = wt[(size_t)(uint32_t)j3 * OSTRIDE + o];
        float f4 = wt[(size_t)(uint32_t)j4 * OSTRIDE + o];
        float f5 = wt[(size_t)(uint32_t)j5 * OSTRIDE + o];
        float f6 = wt[(size_t)(uint32_t)j6 * OSTRIDE + o];
        float f7 = wt[(size_t)(uint32_t)j7 * OSTRIDE + o];
        a0 += (double)f0; a1 += (double)f1; a2 += (double)f2; a3 += (double)f3;
        a0 += (double)f4; a1 += (double)f5; a2 += (double)f6; a3 += (double)f7;
      }
      for (; i < i1; ++i) {
        int j = __builtin_amdgcn_readfirstlane((int)permS[i]);
        a0 += (double)wt[(size_t)(uint32_t)j * OSTRIDE + o];
      }
      bs[k] = (a0 + a1) + (a2 + a3);
    }

    // Combine halves at bucket-sum level (2 chunks of 16 through 32 KB LDS).
    __syncthreads();                   // also guards cshare reuse across zt
    if (half) {
#pragma unroll
      for (int k = 1; k <= 16; ++k) cshare[k - 1][col] = bs[k];
    }
    __syncthreads();
    if (!half) {
#pragma unroll
      for (int k = 1; k <= 16; ++k) bs[k] += cshare[k - 1][col];
    }
    __syncthreads();
    if (half) {
#pragma unroll
      for (int k = 17; k <= 32; ++k) cshare[k - 17][col] = bs[k];
    }
    __syncthreads();
    if (!half) {
#pragma unroll
      for (int k = 17; k <= 32; ++k) bs[k] += cshare[k - 17][col];

      // Membrane scan: 528 compile-time-selected fp64 adds, no masks.
      double memb = 0.0;
      int cnt = 0;
#pragma unroll
      for (int t = 0; t < 32; ++t) {
#pragma unroll
        for (int k = 1; k <= 32; ++k)
          if ((spike_pattern_ct(k) >> t) & 1u) memb += bs[k];
        if (memb > th) { memb -= th; ++cnt; }   // strict: threshold < memb
      }
      cnt_out[(size_t)b * OSTRIDE + o] = cnt;
    }
  }
}

__global__ void write_out_k(const int* __restrict__ cnt2, const int* __restrict__ idx_out,
                            float* __restrict__ out) {
  int i = blockIdx.x * 256 + threadIdx.x;
  if (i >= NB * NOUT) return;
  int b = i / NOUT;
  int r = i - b * NOUT;
  out[i] = (float)cnt2[b * D1 + idx_out[r]];
}

// ---------------------------------------------------------------------------
extern "C" void kernel_launch(void* const* d_in, const int* in_sizes, int n_in,
                              void* d_out, int out_size, void* d_ws, size_t ws_size,
                              hipStream_t stream) {
  const float* x      = (const float*)d_in[0];
  const float* w0     = (const float*)d_in[1];
  const float* t0     = (const float*)d_in[2];
  const float* w2     = (const float*)d_in[3];
  const float* t2     = (const float*)d_in[4];
  const int*   idx0   = (const int*)d_in[5];
  const int*   idx1   = (const int*)d_in[6];
  const int*   idx2   = (const int*)d_in[7];
  const int*   idx_out= (const int*)d_in[8];
  float* out = (float*)d_out;

  char* ws = (char*)d_ws;
  float*    w0T    = (float*)ws;    ws += (size_t)D0 * D0 * 4;   // 64 MB
  float*    w2T    = (float*)ws;    ws += (size_t)D1 * D1 * 4;   // 4 MB
  uint16_t* perm0  = (uint16_t*)ws; ws += (size_t)NB * D0 * 2;
  uint16_t* perm2  = (uint16_t*)ws; ws += (size_t)NB * D1 * 2;
  int*      k0     = (int*)ws;      ws += (size_t)NB * D0 * 4;
  int*      cnt2   = (int*)ws;      ws += (size_t)NB * D1 * 4;
  int*      starts0= (int*)ws;      ws += (size_t)NB * 34 * 4;
  int*      starts2= (int*)ws;      ws += (size_t)NB * 34 * 4;

  transpose_w0_k<<<dim3(D0 / 32, D0 / 32), dim3(8, 32), 0, stream>>>(w0, w0T);
  transpose_w2_k<<<dim3(D1 / 32, D1 / 32), dim3(8, 32), 0, stream>>>(w2, w2T);
  prep_sort0_k<<<NB, 256, 0, stream>>>(x, idx0, perm0, starts0);
  // 512 blocks x 512 thr = 2 blocks/CU = 16 waves/CU; XCD x streams ONE 4 MB
  // o-slice at a time (tiles x, then x+8 via zt loop); perm is LDS-resident.
  lif_core_k<D0, D0, 2><<<dim3(8, NB, 1), 512, 0, stream>>>(w0T, perm0, starts0, t0, k0);
  prep_sort1_k<<<NB, 256, 0, stream>>>(k0, idx1, idx2, perm2, starts2);
  lif_core_k<D1, D1, 1><<<dim3(4, NB, 1), 512, 0, stream>>>(w2T, perm2, starts2, t2, cnt2);
  write_out_k<<<(NB * NOUT + 255) / 256, 256, 0, stream>>>(cnt2, idx_out, out);
}

// Round 8
// 384.921 us; speedup vs baseline: 1.2008x; 1.1240x over previous
//
#include <hip/hip_runtime.h>
#include <stdint.h>
#include <stddef.h>

#define D0 4096
#define D1 1024
#define NOUT 1000
#define NB 64
#define PD0 4352   // D0 + 33 buckets x up-to-7 pad, rounded; 8-aligned buckets
#define PD1 1264

// ---------------------------------------------------------------------------
// Compile-time fp32-faithful spike pattern, N in [0,32] -> 32-bit cycle mask.
// Replicates runtime fp32 semantics EXACTLY: spacing = fl32(32/N), spike at c
// iff fmodf(c, spacing) < 1.  (Integer shortcut is NOT equivalent.)
// ---------------------------------------------------------------------------
constexpr uint32_t spike_pattern_ct(int N) {
  if (N <= 0) return 0u;
  if (N >= 32) return 0xFFFFFFFFu;
  float sp = 32.0f / (float)N;
  uint32_t m = 0;
  for (int c = 0; c < 32; ++c) {
    double q = (double)c / (double)sp;
    int n = (int)q;                       // trunc, q >= 0
    double r = (double)c - (double)n * (double)sp;   // == fmodf(c, sp), exact
    if (r < 1.0) m |= (1u << c);
  }
  return m;
}

// ---------------------------------------------------------------------------
// Transpose w0 (4096x4096) -> w0T[j][o].  float4 on both global sides.
// ---------------------------------------------------------------------------
__global__ void transpose_w0_k(const float* __restrict__ w, float* __restrict__ wt) {
  __shared__ float tile[32][33];
  int j0 = blockIdx.x * 32;
  int o0 = blockIdx.y * 32;
  int tx = threadIdx.x, ty = threadIdx.y;
  float4 v = *reinterpret_cast<const float4*>(&w[(size_t)(o0 + ty) * D0 + j0 + 4 * tx]);
  tile[ty][4 * tx + 0] = v.x;
  tile[ty][4 * tx + 1] = v.y;
  tile[ty][4 * tx + 2] = v.z;
  tile[ty][4 * tx + 3] = v.w;
  __syncthreads();
  float4 u;
  u.x = tile[4 * tx + 0][ty];
  u.y = tile[4 * tx + 1][ty];
  u.z = tile[4 * tx + 2][ty];
  u.w = tile[4 * tx + 3][ty];
  *reinterpret_cast<float4*>(&wt[(size_t)(j0 + ty) * D0 + o0 + 4 * tx]) = u;
}

// Transpose w2 (1000x1024) -> w2T[j][o], o padded to 1024 with zeros.
__global__ void transpose_w2_k(const float* __restrict__ w, float* __restrict__ wt) {
  __shared__ float tile[32][33];
  int j0 = blockIdx.x * 32;
  int o0 = blockIdx.y * 32;
  int tx = threadIdx.x, ty = threadIdx.y;
  int o = o0 + ty;
  float4 v = make_float4(0.f, 0.f, 0.f, 0.f);
  if (o < NOUT) v = *reinterpret_cast<const float4*>(&w[(size_t)o * D1 + j0 + 4 * tx]);
  tile[ty][4 * tx + 0] = v.x;
  tile[ty][4 * tx + 1] = v.y;
  tile[ty][4 * tx + 2] = v.z;
  tile[ty][4 * tx + 3] = v.w;
  __syncthreads();
  float4 u;
  u.x = tile[4 * tx + 0][ty];
  u.y = tile[4 * tx + 1][ty];
  u.z = tile[4 * tx + 2][ty];
  u.w = tile[4 * tx + 3][ty];
  *reinterpret_cast<float4*>(&wt[(size_t)(j0 + ty) * D1 + o0 + 4 * tx]) = u;
}

// ---------------------------------------------------------------------------
// Per-batch counting sort with 8-ALIGNED bucket starts (pad slots = 0 so a
// masked tail group gathers row 0 and masks it — no OOB, no serial tail).
// starts layout per batch: [0..33] aligned starts (34), [34..66] true lens.
// prep_sort0: key = rint(x[b][idx0[j]]*32) (compute_N0 fused).
// ---------------------------------------------------------------------------
__global__ void prep_sort0_k(const float* __restrict__ x, const int* __restrict__ idx0,
                             uint16_t* __restrict__ perm, int* __restrict__ starts) {
  __shared__ int keys[D0];
  __shared__ int hist[33];
  __shared__ int base[34];
  __shared__ int cursor[33];
  int b = blockIdx.x;
  int tid = threadIdx.x;
  if (tid < 33) hist[tid] = 0;
  for (int p = tid; p < PD0; p += 256) perm[(size_t)b * PD0 + p] = 0;
  __syncthreads();
  for (int j = tid; j < D0; j += 256) {
    int k = (int)rintf(x[b * D0 + idx0[j]] * 32.0f);
    keys[j] = k;
    atomicAdd(&hist[k], 1);
  }
  __syncthreads();
  if (tid == 0) {
    int s = 0;
    for (int k = 0; k < 33; ++k) {
      base[k] = s; cursor[k] = s;
      s = (s + hist[k] + 7) & ~7;        // 8-aligned next start
    }
    base[33] = s;
  }
  __syncthreads();
  if (tid < 34) starts[b * 68 + tid] = base[tid];
  if (tid < 33) starts[b * 68 + 34 + tid] = hist[tid];
  for (int j = tid; j < D0; j += 256) {
    int k = keys[j];
    int pos = atomicAdd(&cursor[k], 1);
    perm[(size_t)b * PD0 + pos] = (uint16_t)j;
  }
}

// prep_sort1: key from pooled spike counts (pool_encode fused).
__global__ void prep_sort1_k(const int* __restrict__ k0, const int* __restrict__ idx1,
                             const int* __restrict__ idx2,
                             uint16_t* __restrict__ perm, int* __restrict__ starts) {
  __shared__ int keys[D1];
  __shared__ int hist[33];
  __shared__ int base[34];
  __shared__ int cursor[33];
  int b = blockIdx.x;
  int tid = threadIdx.x;
  if (tid < 33) hist[tid] = 0;
  for (int p = tid; p < PD1; p += 256) perm[(size_t)b * PD1 + p] = 0;
  __syncthreads();
  for (int j = tid; j < D1; j += 256) {
    int q2 = idx2[j];
    int c = q2 >> 4;
    int h2 = (q2 >> 2) & 3;
    int w2 = q2 & 3;
    int cnt = 0;
#pragma unroll
    for (int dh = 0; dh < 2; ++dh)
#pragma unroll
      for (int dw = 0; dw < 2; ++dw) {
        int q = c * 64 + (2 * h2 + dh) * 8 + (2 * w2 + dw);
        cnt += k0[b * D0 + idx1[q]];
      }
    int k = (int)rintf((float)cnt * 0.25f);
    keys[j] = k;
    atomicAdd(&hist[k], 1);
  }
  __syncthreads();
  if (tid == 0) {
    int s = 0;
    for (int k = 0; k < 33; ++k) {
      base[k] = s; cursor[k] = s;
      s = (s + hist[k] + 7) & ~7;
    }
    base[33] = s;
  }
  __syncthreads();
  if (tid < 34) starts[b * 68 + tid] = base[tid];
  if (tid < 33) starts[b * 68 + 34 + tid] = hist[tid];
  for (int j = tid; j < D1; j += 256) {
    int k = keys[j];
    int pos = atomicAdd(&cursor[k], 1);
    perm[(size_t)b * PD1 + pos] = (uint16_t)j;
  }
}

// ---------------------------------------------------------------------------
// LIF core, bucket decomposition, fp64-exact.
//
// Round-7 evidence: FETCH at ideal (67 MB) but dur flat — VALU (~144us) and
// L2 delivery (~125us) ALTERNATE per 8-group (vmcnt(0) drain), summing to
// 283us.  Round-8 forces overlap:
//  * depth-2 group pipeline: G(n+1)'s 8 gathers issue BEFORE G(n)'s fp64
//    accumulate; compiler emits counted vmcnt, so ~8 loads stay in flight
//    through the VALU phase.
//  * one ds_read_b128 + 4 readfirstlane + SALU unpack per 8 indices (perm
//    buckets 8-aligned in LDS) — removes round-7's per-element ds+rfl VALU.
//  * masked aligned tail group (pad zeros -> row-0 gather, scalar-masked)
//    replaces up-to-7 serial full-latency tail loads; only one half of the
//    j-split ever has a tail (mid rounded to 8).
// ---------------------------------------------------------------------------
template <int D, int PD, int OSTRIDE, int TILES>
__launch_bounds__(512, 2)
__global__ void lif_core_k(const float* __restrict__ wt, const uint16_t* __restrict__ perm,
                           const int* __restrict__ starts, const float* __restrict__ thr_p,
                           int* __restrict__ cnt_out) {
  __shared__ double cshare[16][256];   // 32 KB: bucket-sum exchange, 2 chunks
  __shared__ uint16_t permS[PD];
  int tid = threadIdx.x;
  int b = blockIdx.y;
  int col = tid & 255;
  int half = __builtin_amdgcn_readfirstlane(tid >> 8);  // waves 0-3 -> 0, 4-7 -> 1

  // Stage this batch's (aligned, zero-padded) perm into LDS.
  {
    const ushort2* p2 = reinterpret_cast<const ushort2*>(perm + (size_t)b * PD);
    ushort2* s2 = reinterpret_cast<ushort2*>(permS);
    for (int i = tid; i < PD / 2; i += 512) s2[i] = p2[i];
  }
  __syncthreads();

  const int* stA = starts + b * 68;        // aligned starts[34]
  const int* stL = starts + b * 68 + 34;   // true lens[33]
  double th = (double)thr_p[0];

#define RDIDX(P) do { \
    const uint32_t* _q = reinterpret_cast<const uint32_t*>(permS + ip); \
    uint32_t _w0 = _q[0], _w1 = _q[1], _w2 = _q[2], _w3 = _q[3]; \
    uint32_t _s0 = __builtin_amdgcn_readfirstlane(_w0); \
    uint32_t _s1 = __builtin_amdgcn_readfirstlane(_w1); \
    uint32_t _s2 = __builtin_amdgcn_readfirstlane(_w2); \
    uint32_t _s3 = __builtin_amdgcn_readfirstlane(_w3); \
    P##0 = _s0 & 0xffffu; P##1 = _s0 >> 16; \
    P##2 = _s1 & 0xffffu; P##3 = _s1 >> 16; \
    P##4 = _s2 & 0xffffu; P##5 = _s2 >> 16; \
    P##6 = _s3 & 0xffffu; P##7 = _s3 >> 16; \
    ip += 8; \
  } while (0)

#define GATHER(F, P) do { \
    F##0 = wt[(size_t)P##0 * OSTRIDE + o]; \
    F##1 = wt[(size_t)P##1 * OSTRIDE + o]; \
    F##2 = wt[(size_t)P##2 * OSTRIDE + o]; \
    F##3 = wt[(size_t)P##3 * OSTRIDE + o]; \
    F##4 = wt[(size_t)P##4 * OSTRIDE + o]; \
    F##5 = wt[(size_t)P##5 * OSTRIDE + o]; \
    F##6 = wt[(size_t)P##6 * OSTRIDE + o]; \
    F##7 = wt[(size_t)P##7 * OSTRIDE + o]; \
  } while (0)

#define ACC8(F) do { \
    a0 += (double)F##0; a1 += (double)F##1; a2 += (double)F##2; a3 += (double)F##3; \
    a0 += (double)F##4; a1 += (double)F##5; a2 += (double)F##6; a3 += (double)F##7; \
  } while (0)

  for (int zt = 0; zt < TILES; ++zt) {
    int o = (blockIdx.x + gridDim.x * zt) * 256 + col;

    double bs[33];
#pragma unroll
    for (int k = 1; k <= 32; ++k) bs[k] = 0.0;

#pragma unroll
    for (int k = 1; k <= 32; ++k) {    // k=0: empty pattern, segment skipped
      int hs0 = __builtin_amdgcn_readfirstlane(stA[k]);
      int len = __builtin_amdgcn_readfirstlane(stL[k]);
      if (len == 0) continue;          // scalar branch
      int half_lo = ((len >> 1) + 7) & ~7;
      int mid8 = half_lo < len ? half_lo : len;   // lower count, 8-aligned or ==len
      int ip  = half ? hs0 + mid8 : hs0;          // my start (8-aligned when nonempty)
      int myn = half ? len - mid8 : mid8;
      if (myn == 0) continue;
      int ng = myn >> 3, rem = myn & 7;
      uint32_t pA0, pA1, pA2, pA3, pA4, pA5, pA6, pA7;
      uint32_t pB0, pB1, pB2, pB3, pB4, pB5, pB6, pB7;
      float fA0, fA1, fA2, fA3, fA4, fA5, fA6, fA7;
      float fB0, fB1, fB2, fB3, fB4, fB5, fB6, fB7;
      double a0 = 0.0, a1 = 0.0, a2 = 0.0, a3 = 0.0;
      if (ng > 0) {
        RDIDX(pA); GATHER(fA, pA);
        int g = 1;
        for (; g + 1 < ng; g += 2) {
          RDIDX(pB); GATHER(fB, pB);   // next group in flight...
          ACC8(fA);                    // ...while this one accumulates
          RDIDX(pA); GATHER(fA, pA);
          ACC8(fB);
        }
        if (g < ng) {
          RDIDX(pB); GATHER(fB, pB);
          ACC8(fA);
          ACC8(fB);
        } else {
          ACC8(fA);
        }
      }
      if (rem) {                       // aligned masked tail (pad reads row 0)
        RDIDX(pA); GATHER(fA, pA);
        a0 += (double)fA0;             // rem >= 1 always here
        if (rem > 1) a1 += (double)fA1;
        if (rem > 2) a2 += (double)fA2;
        if (rem > 3) a3 += (double)fA3;
        if (rem > 4) a0 += (double)fA4;
        if (rem > 5) a1 += (double)fA5;
        if (rem > 6) a2 += (double)fA6;
      }
      bs[k] = (a0 + a1) + (a2 + a3);
    }

    // Combine halves at bucket-sum level (2 chunks of 16 through 32 KB LDS).
    __syncthreads();                   // also guards cshare reuse across zt
    if (half) {
#pragma unroll
      for (int k = 1; k <= 16; ++k) cshare[k - 1][col] = bs[k];
    }
    __syncthreads();
    if (!half) {
#pragma unroll
      for (int k = 1; k <= 16; ++k) bs[k] += cshare[k - 1][col];
    }
    __syncthreads();
    if (half) {
#pragma unroll
      for (int k = 17; k <= 32; ++k) cshare[k - 17][col] = bs[k];
    }
    __syncthreads();
    if (!half) {
#pragma unroll
      for (int k = 17; k <= 32; ++k) bs[k] += cshare[k - 17][col];

      // Membrane scan: 528 compile-time-selected fp64 adds, no masks.
      double memb = 0.0;
      int cnt = 0;
#pragma unroll
      for (int t = 0; t < 32; ++t) {
#pragma unroll
        for (int k = 1; k <= 32; ++k)
          if ((spike_pattern_ct(k) >> t) & 1u) memb += bs[k];
        if (memb > th) { memb -= th; ++cnt; }   // strict: threshold < memb
      }
      cnt_out[(size_t)b * OSTRIDE + o] = cnt;
    }
  }
#undef RDIDX
#undef GATHER
#undef ACC8
}

__global__ void write_out_k(const int* __restrict__ cnt2, const int* __restrict__ idx_out,
                            float* __restrict__ out) {
  int i = blockIdx.x * 256 + threadIdx.x;
  if (i >= NB * NOUT) return;
  int b = i / NOUT;
  int r = i - b * NOUT;
  out[i] = (float)cnt2[b * D1 + idx_out[r]];
}

// ---------------------------------------------------------------------------
extern "C" void kernel_launch(void* const* d_in, const int* in_sizes, int n_in,
                              void* d_out, int out_size, void* d_ws, size_t ws_size,
                              hipStream_t stream) {
  const float* x      = (const float*)d_in[0];
  const float* w0     = (const float*)d_in[1];
  const float* t0     = (const float*)d_in[2];
  const float* w2     = (const float*)d_in[3];
  const float* t2     = (const float*)d_in[4];
  const int*   idx0   = (const int*)d_in[5];
  const int*   idx1   = (const int*)d_in[6];
  const int*   idx2   = (const int*)d_in[7];
  const int*   idx_out= (const int*)d_in[8];
  float* out = (float*)d_out;

  char* ws = (char*)d_ws;
  float*    w0T    = (float*)ws;    ws += (size_t)D0 * D0 * 4;   // 64 MB
  float*    w2T    = (float*)ws;    ws += (size_t)D1 * D1 * 4;   // 4 MB
  uint16_t* perm0  = (uint16_t*)ws; ws += (size_t)NB * PD0 * 2;
  uint16_t* perm2  = (uint16_t*)ws; ws += (size_t)NB * PD1 * 2;
  int*      k0     = (int*)ws;      ws += (size_t)NB * D0 * 4;
  int*      cnt2   = (int*)ws;      ws += (size_t)NB * D1 * 4;
  int*      starts0= (int*)ws;      ws += (size_t)NB * 68 * 4;
  int*      starts2= (int*)ws;      ws += (size_t)NB * 68 * 4;

  transpose_w0_k<<<dim3(D0 / 32, D0 / 32), dim3(8, 32), 0, stream>>>(w0, w0T);
  transpose_w2_k<<<dim3(D1 / 32, D1 / 32), dim3(8, 32), 0, stream>>>(w2, w2T);
  prep_sort0_k<<<NB, 256, 0, stream>>>(x, idx0, perm0, starts0);
  // 512 blocks x 512 thr = 2 blocks/CU = 16 waves/CU; XCD x streams ONE 4 MB
  // o-slice at a time (tiles x, then x+8 via zt loop); perm is LDS-resident.
  lif_core_k<D0, PD0, D0, 2><<<dim3(8, NB, 1), 512, 0, stream>>>(w0T, perm0, starts0, t0, k0);
  prep_sort1_k<<<NB, 256, 0, stream>>>(k0, idx1, idx2, perm2, starts2);
  lif_core_k<D1, PD1, D1, 1><<<dim3(4, NB, 1), 512, 0, stream>>>(w2T, perm2, starts2, t2, cnt2);
  write_out_k<<<(NB * NOUT + 255) / 256, 256, 0, stream>>>(cnt2, idx_out, out);
}

// Round 9
// 361.552 us; speedup vs baseline: 1.2784x; 1.0646x over previous
//
#include <hip/hip_runtime.h>
#include <stdint.h>
#include <stddef.h>

#define D0 4096
#define D1 1024
#define NOUT 1000
#define NB 64
#define PD0 4352   // 8-aligned, zero-padded bucket storage
#define PD1 1264

// ---------------------------------------------------------------------------
// Compile-time fp32-faithful spike pattern, N in [0,32] -> 32-bit cycle mask.
// Replicates runtime fp32 semantics EXACTLY: spacing = fl32(32/N), spike at c
// iff fmodf(c, spacing) < 1.  (Integer shortcut is NOT equivalent.)
// ---------------------------------------------------------------------------
constexpr uint32_t spike_pattern_ct(int N) {
  if (N <= 0) return 0u;
  if (N >= 32) return 0xFFFFFFFFu;
  float sp = 32.0f / (float)N;
  uint32_t m = 0;
  for (int c = 0; c < 32; ++c) {
    double q = (double)c / (double)sp;
    int n = (int)q;                       // trunc, q >= 0
    double r = (double)c - (double)n * (double)sp;   // == fmodf(c, sp), exact
    if (r < 1.0) m |= (1u << c);
  }
  return m;
}

// ---------------------------------------------------------------------------
// Transpose w0 (4096x4096) -> w0T[j][o].  float4 on both global sides.
// ---------------------------------------------------------------------------
__global__ void transpose_w0_k(const float* __restrict__ w, float* __restrict__ wt) {
  __shared__ float tile[32][33];
  int j0 = blockIdx.x * 32;
  int o0 = blockIdx.y * 32;
  int tx = threadIdx.x, ty = threadIdx.y;
  float4 v = *reinterpret_cast<const float4*>(&w[(size_t)(o0 + ty) * D0 + j0 + 4 * tx]);
  tile[ty][4 * tx + 0] = v.x;
  tile[ty][4 * tx + 1] = v.y;
  tile[ty][4 * tx + 2] = v.z;
  tile[ty][4 * tx + 3] = v.w;
  __syncthreads();
  float4 u;
  u.x = tile[4 * tx + 0][ty];
  u.y = tile[4 * tx + 1][ty];
  u.z = tile[4 * tx + 2][ty];
  u.w = tile[4 * tx + 3][ty];
  *reinterpret_cast<float4*>(&wt[(size_t)(j0 + ty) * D0 + o0 + 4 * tx]) = u;
}

// Transpose w2 (1000x1024) -> w2T[j][o], o padded to 1024 with zeros.
__global__ void transpose_w2_k(const float* __restrict__ w, float* __restrict__ wt) {
  __shared__ float tile[32][33];
  int j0 = blockIdx.x * 32;
  int o0 = blockIdx.y * 32;
  int tx = threadIdx.x, ty = threadIdx.y;
  int o = o0 + ty;
  float4 v = make_float4(0.f, 0.f, 0.f, 0.f);
  if (o < NOUT) v = *reinterpret_cast<const float4*>(&w[(size_t)o * D1 + j0 + 4 * tx]);
  tile[ty][4 * tx + 0] = v.x;
  tile[ty][4 * tx + 1] = v.y;
  tile[ty][4 * tx + 2] = v.z;
  tile[ty][4 * tx + 3] = v.w;
  __syncthreads();
  float4 u;
  u.x = tile[4 * tx + 0][ty];
  u.y = tile[4 * tx + 1][ty];
  u.z = tile[4 * tx + 2][ty];
  u.w = tile[4 * tx + 3][ty];
  *reinterpret_cast<float4*>(&wt[(size_t)(j0 + ty) * D1 + o0 + 4 * tx]) = u;
}

// ---------------------------------------------------------------------------
// Per-batch counting sort with 8-ALIGNED bucket starts (pad slots = 0 so a
// masked tail group gathers row 0 and masks it — no OOB, no serial tail).
// starts layout per batch: [0..33] aligned starts (34), [34..66] true lens.
// prep_sort0: key = rint(x[b][idx0[j]]*32) (compute_N0 fused).
// ---------------------------------------------------------------------------
__global__ void prep_sort0_k(const float* __restrict__ x, const int* __restrict__ idx0,
                             uint16_t* __restrict__ perm, int* __restrict__ starts) {
  __shared__ int keys[D0];
  __shared__ int hist[33];
  __shared__ int base[34];
  __shared__ int cursor[33];
  int b = blockIdx.x;
  int tid = threadIdx.x;
  if (tid < 33) hist[tid] = 0;
  for (int p = tid; p < PD0; p += 256) perm[(size_t)b * PD0 + p] = 0;
  __syncthreads();
  for (int j = tid; j < D0; j += 256) {
    int k = (int)rintf(x[b * D0 + idx0[j]] * 32.0f);
    keys[j] = k;
    atomicAdd(&hist[k], 1);
  }
  __syncthreads();
  if (tid == 0) {
    int s = 0;
    for (int k = 0; k < 33; ++k) {
      base[k] = s; cursor[k] = s;
      s = (s + hist[k] + 7) & ~7;        // 8-aligned next start
    }
    base[33] = s;
  }
  __syncthreads();
  if (tid < 34) starts[b * 68 + tid] = base[tid];
  if (tid < 33) starts[b * 68 + 34 + tid] = hist[tid];
  for (int j = tid; j < D0; j += 256) {
    int k = keys[j];
    int pos = atomicAdd(&cursor[k], 1);
    perm[(size_t)b * PD0 + pos] = (uint16_t)j;
  }
}

// prep_sort1: key from pooled spike counts (pool_encode fused).
__global__ void prep_sort1_k(const int* __restrict__ k0, const int* __restrict__ idx1,
                             const int* __restrict__ idx2,
                             uint16_t* __restrict__ perm, int* __restrict__ starts) {
  __shared__ int keys[D1];
  __shared__ int hist[33];
  __shared__ int base[34];
  __shared__ int cursor[33];
  int b = blockIdx.x;
  int tid = threadIdx.x;
  if (tid < 33) hist[tid] = 0;
  for (int p = tid; p < PD1; p += 256) perm[(size_t)b * PD1 + p] = 0;
  __syncthreads();
  for (int j = tid; j < D1; j += 256) {
    int q2 = idx2[j];
    int c = q2 >> 4;
    int h2 = (q2 >> 2) & 3;
    int w2 = q2 & 3;
    int cnt = 0;
#pragma unroll
    for (int dh = 0; dh < 2; ++dh)
#pragma unroll
      for (int dw = 0; dw < 2; ++dw) {
        int q = c * 64 + (2 * h2 + dh) * 8 + (2 * w2 + dw);
        cnt += k0[b * D0 + idx1[q]];
      }
    int k = (int)rintf((float)cnt * 0.25f);
    keys[j] = k;
    atomicAdd(&hist[k], 1);
  }
  __syncthreads();
  if (tid == 0) {
    int s = 0;
    for (int k = 0; k < 33; ++k) {
      base[k] = s; cursor[k] = s;
      s = (s + hist[k] + 7) & ~7;
    }
    base[33] = s;
  }
  __syncthreads();
  if (tid < 34) starts[b * 68 + tid] = base[tid];
  if (tid < 33) starts[b * 68 + 34 + tid] = hist[tid];
  for (int j = tid; j < D1; j += 256) {
    int k = keys[j];
    int pos = atomicAdd(&cursor[k], 1);
    perm[(size_t)b * PD1 + pos] = (uint16_t)j;
  }
}

// ---------------------------------------------------------------------------
// LIF core, bucket decomposition, fp64-exact.
//
// Round-8 evidence: VALU (~127us) and L2 delivery (~125us) overlap only ~half
// (dur 233, VALUBusy 54%, Occ 41%).  Per-wave pipelining is maxed (round-6
// showed deeper = footprint regression) — so buy overlap with OCCUPANCY:
//  * 1024-thread blocks, grid (8,NB), TILES=2: same 512 blocks, same
//    one-4MB-slice-per-XCD L2 layout, but 2 blocks/CU x 16 waves = 32
//    waves/CU (was 16).
//  * BUCKET-split (not j-split): 4 groups of 256 threads; group g owns
//    buckets k = 4i+g+1 (stride-4 interleave balances group loads).  Each
//    thread keeps only bs[8] = 16 VGPRs -> total ~50 VGPR, fits the 64-cap
//    that 8 waves/SIMD requires (__launch_bounds__(1024, 8)).
//  * No combine adds (disjoint k): groups 1-3 publish bs[8] to cshare[24][256],
//    group 0 runs the compile-time-mask membrane scan (LDS values CSE'd).
// Inner loop unchanged from round 8 (depth-2 gather pipeline, ds_read_b128
// index quads, masked aligned tails on zero-padded buckets).
// ---------------------------------------------------------------------------
template <int D, int PD, int OSTRIDE, int TILES>
__launch_bounds__(1024, 8)
__global__ void lif_core_k(const float* __restrict__ wt, const uint16_t* __restrict__ perm,
                           const int* __restrict__ starts, const float* __restrict__ thr_p,
                           int* __restrict__ cnt_out) {
  __shared__ double cshare[24][256];   // 48 KB: groups 1-3 publish bs[8]
  __shared__ uint16_t permS[PD];
  int tid = threadIdx.x;
  int b = blockIdx.y;
  int col = tid & 255;
  int g = __builtin_amdgcn_readfirstlane(tid >> 8);   // group 0..3, wave-uniform

  // Stage this batch's (aligned, zero-padded) perm into LDS.
  {
    const ushort2* p2 = reinterpret_cast<const ushort2*>(perm + (size_t)b * PD);
    ushort2* s2 = reinterpret_cast<ushort2*>(permS);
    for (int i = tid; i < PD / 2; i += 1024) s2[i] = p2[i];
  }
  __syncthreads();

  const int* stA = starts + b * 68;        // aligned starts[34]
  const int* stL = starts + b * 68 + 34;   // true lens[33]
  double th = (double)thr_p[0];

#define RDIDX(P) do { \
    const uint32_t* _q = reinterpret_cast<const uint32_t*>(permS + ip); \
    uint32_t _w0 = _q[0], _w1 = _q[1], _w2 = _q[2], _w3 = _q[3]; \
    uint32_t _s0 = __builtin_amdgcn_readfirstlane(_w0); \
    uint32_t _s1 = __builtin_amdgcn_readfirstlane(_w1); \
    uint32_t _s2 = __builtin_amdgcn_readfirstlane(_w2); \
    uint32_t _s3 = __builtin_amdgcn_readfirstlane(_w3); \
    P##0 = _s0 & 0xffffu; P##1 = _s0 >> 16; \
    P##2 = _s1 & 0xffffu; P##3 = _s1 >> 16; \
    P##4 = _s2 & 0xffffu; P##5 = _s2 >> 16; \
    P##6 = _s3 & 0xffffu; P##7 = _s3 >> 16; \
    ip += 8; \
  } while (0)

#define GATHER(F, P) do { \
    F##0 = wt[(size_t)P##0 * OSTRIDE + o]; \
    F##1 = wt[(size_t)P##1 * OSTRIDE + o]; \
    F##2 = wt[(size_t)P##2 * OSTRIDE + o]; \
    F##3 = wt[(size_t)P##3 * OSTRIDE + o]; \
    F##4 = wt[(size_t)P##4 * OSTRIDE + o]; \
    F##5 = wt[(size_t)P##5 * OSTRIDE + o]; \
    F##6 = wt[(size_t)P##6 * OSTRIDE + o]; \
    F##7 = wt[(size_t)P##7 * OSTRIDE + o]; \
  } while (0)

#define ACC8(F) do { \
    a0 += (double)F##0; a1 += (double)F##1; a2 += (double)F##2; a3 += (double)F##3; \
    a0 += (double)F##4; a1 += (double)F##5; a2 += (double)F##6; a3 += (double)F##7; \
  } while (0)

  for (int zt = 0; zt < TILES; ++zt) {
    int o = (blockIdx.x + gridDim.x * zt) * 256 + col;

    double bs[8];
#pragma unroll
    for (int i = 0; i < 8; ++i) bs[i] = 0.0;

#pragma unroll
    for (int i = 0; i < 8; ++i) {
      int k = 4 * i + g + 1;           // this group's i-th bucket (1..32)
      int hs0 = __builtin_amdgcn_readfirstlane(stA[k]);
      int len = __builtin_amdgcn_readfirstlane(stL[k]);
      if (len == 0) continue;          // scalar branch
      int ip = hs0;
      int ng = len >> 3, rem = len & 7;
      uint32_t pA0, pA1, pA2, pA3, pA4, pA5, pA6, pA7;
      uint32_t pB0, pB1, pB2, pB3, pB4, pB5, pB6, pB7;
      float fA0, fA1, fA2, fA3, fA4, fA5, fA6, fA7;
      float fB0, fB1, fB2, fB3, fB4, fB5, fB6, fB7;
      double a0 = 0.0, a1 = 0.0, a2 = 0.0, a3 = 0.0;
      if (ng > 0) {
        RDIDX(pA); GATHER(fA, pA);
        int gg = 1;
        for (; gg + 1 < ng; gg += 2) {
          RDIDX(pB); GATHER(fB, pB);   // next group in flight...
          ACC8(fA);                    // ...while this one accumulates
          RDIDX(pA); GATHER(fA, pA);
          ACC8(fB);
        }
        if (gg < ng) {
          RDIDX(pB); GATHER(fB, pB);
          ACC8(fA);
          ACC8(fB);
        } else {
          ACC8(fA);
        }
      }
      if (rem) {                       // aligned masked tail (pad reads row 0)
        RDIDX(pA); GATHER(fA, pA);
        a0 += (double)fA0;             // rem >= 1 always here
        if (rem > 1) a1 += (double)fA1;
        if (rem > 2) a2 += (double)fA2;
        if (rem > 3) a3 += (double)fA3;
        if (rem > 4) a0 += (double)fA4;
        if (rem > 5) a1 += (double)fA5;
        if (rem > 6) a2 += (double)fA6;
      }
      bs[i] = (a0 + a1) + (a2 + a3);
    }

    // Groups 1-3 publish their bucket sums; group 0 scans.
    __syncthreads();                   // zt>0: also fences prior scan reads
    if (g > 0) {
#pragma unroll
      for (int i = 0; i < 8; ++i) cshare[(g - 1) * 8 + i][col] = bs[i];
    }
    __syncthreads();
    if (g == 0) {
      // Membrane scan: 528 compile-time-selected fp64 adds; the 24
      // LDS-resident bucket sums are loop-invariant (compiler CSEs to regs).
      double memb = 0.0;
      int cnt = 0;
#pragma unroll
      for (int t = 0; t < 32; ++t) {
#pragma unroll
        for (int k = 1; k <= 32; ++k)
          if ((spike_pattern_ct(k) >> t) & 1u) {
            constexpr_int:;
            const int gi = (k - 1) & 3;
            const int ii = (k - 1) >> 2;
            double v = (gi == 0) ? bs[ii] : cshare[(gi - 1) * 8 + ii][col];
            memb += v;
          }
        if (memb > th) { memb -= th; ++cnt; }   // strict: threshold < memb
      }
      cnt_out[(size_t)b * OSTRIDE + o] = cnt;
    }
  }
#undef RDIDX
#undef GATHER
#undef ACC8
}

__global__ void write_out_k(const int* __restrict__ cnt2, const int* __restrict__ idx_out,
                            float* __restrict__ out) {
  int i = blockIdx.x * 256 + threadIdx.x;
  if (i >= NB * NOUT) return;
  int b = i / NOUT;
  int r = i - b * NOUT;
  out[i] = (float)cnt2[b * D1 + idx_out[r]];
}

// ---------------------------------------------------------------------------
extern "C" void kernel_launch(void* const* d_in, const int* in_sizes, int n_in,
                              void* d_out, int out_size, void* d_ws, size_t ws_size,
                              hipStream_t stream) {
  const float* x      = (const float*)d_in[0];
  const float* w0     = (const float*)d_in[1];
  const float* t0     = (const float*)d_in[2];
  const float* w2     = (const float*)d_in[3];
  const float* t2     = (const float*)d_in[4];
  const int*   idx0   = (const int*)d_in[5];
  const int*   idx1   = (const int*)d_in[6];
  const int*   idx2   = (const int*)d_in[7];
  const int*   idx_out= (const int*)d_in[8];
  float* out = (float*)d_out;

  char* ws = (char*)d_ws;
  float*    w0T    = (float*)ws;    ws += (size_t)D0 * D0 * 4;   // 64 MB
  float*    w2T    = (float*)ws;    ws += (size_t)D1 * D1 * 4;   // 4 MB
  uint16_t* perm0  = (uint16_t*)ws; ws += (size_t)NB * PD0 * 2;
  uint16_t* perm2  = (uint16_t*)ws; ws += (size_t)NB * PD1 * 2;
  int*      k0     = (int*)ws;      ws += (size_t)NB * D0 * 4;
  int*      cnt2   = (int*)ws;      ws += (size_t)NB * D1 * 4;
  int*      starts0= (int*)ws;      ws += (size_t)NB * 68 * 4;
  int*      starts2= (int*)ws;      ws += (size_t)NB * 68 * 4;

  transpose_w0_k<<<dim3(D0 / 32, D0 / 32), dim3(8, 32), 0, stream>>>(w0, w0T);
  transpose_w2_k<<<dim3(D1 / 32, D1 / 32), dim3(8, 32), 0, stream>>>(w2, w2T);
  prep_sort0_k<<<NB, 256, 0, stream>>>(x, idx0, perm0, starts0);
  // 512 blocks x 1024 thr = 2 blocks/CU = 32 waves/CU; XCD x streams ONE 4 MB
  // o-slice at a time (tiles x, then x+8 via zt loop); perm is LDS-resident.
  lif_core_k<D0, PD0, D0, 2><<<dim3(8, NB, 1), 1024, 0, stream>>>(w0T, perm0, starts0, t0, k0);
  prep_sort1_k<<<NB, 256, 0, stream>>>(k0, idx1, idx2, perm2, starts2);
  lif_core_k<D1, PD1, D1, 1><<<dim3(4, NB, 1), 1024, 0, stream>>>(w2T, perm2, starts2, t2, cnt2);
  write_out_k<<<(NB * NOUT + 255) / 256, 256, 0, stream>>>(cnt2, idx_out, out);
}

// Round 10
// 359.019 us; speedup vs baseline: 1.2874x; 1.0071x over previous
//
#include <hip/hip_runtime.h>
#include <stdint.h>
#include <stddef.h>

#define D0 4096
#define D1 1024
#define NOUT 1000
#define NB 64
#define PD0 4352   // 8-aligned, zero-padded bucket storage
#define PD1 1264

// ---------------------------------------------------------------------------
// Compile-time fp32-faithful spike pattern, N in [0,32] -> 32-bit cycle mask.
// Replicates runtime fp32 semantics EXACTLY: spacing = fl32(32/N), spike at c
// iff fmodf(c, spacing) < 1.  (Integer shortcut is NOT equivalent.)
// ---------------------------------------------------------------------------
constexpr uint32_t spike_pattern_ct(int N) {
  if (N <= 0) return 0u;
  if (N >= 32) return 0xFFFFFFFFu;
  float sp = 32.0f / (float)N;
  uint32_t m = 0;
  for (int c = 0; c < 32; ++c) {
    double q = (double)c / (double)sp;
    int n = (int)q;                       // trunc, q >= 0
    double r = (double)c - (double)n * (double)sp;   // == fmodf(c, sp), exact
    if (r < 1.0) m |= (1u << c);
  }
  return m;
}

// ---------------------------------------------------------------------------
// Transpose w0 (4096x4096) -> w0T[j][o].  float4 on both global sides.
// ---------------------------------------------------------------------------
__global__ void transpose_w0_k(const float* __restrict__ w, float* __restrict__ wt) {
  __shared__ float tile[32][33];
  int j0 = blockIdx.x * 32;
  int o0 = blockIdx.y * 32;
  int tx = threadIdx.x, ty = threadIdx.y;
  float4 v = *reinterpret_cast<const float4*>(&w[(size_t)(o0 + ty) * D0 + j0 + 4 * tx]);
  tile[ty][4 * tx + 0] = v.x;
  tile[ty][4 * tx + 1] = v.y;
  tile[ty][4 * tx + 2] = v.z;
  tile[ty][4 * tx + 3] = v.w;
  __syncthreads();
  float4 u;
  u.x = tile[4 * tx + 0][ty];
  u.y = tile[4 * tx + 1][ty];
  u.z = tile[4 * tx + 2][ty];
  u.w = tile[4 * tx + 3][ty];
  *reinterpret_cast<float4*>(&wt[(size_t)(j0 + ty) * D0 + o0 + 4 * tx]) = u;
}

// Transpose w2 (1000x1024) -> w2T[j][o], o padded to 1024 with zeros.
__global__ void transpose_w2_k(const float* __restrict__ w, float* __restrict__ wt) {
  __shared__ float tile[32][33];
  int j0 = blockIdx.x * 32;
  int o0 = blockIdx.y * 32;
  int tx = threadIdx.x, ty = threadIdx.y;
  int o = o0 + ty;
  float4 v = make_float4(0.f, 0.f, 0.f, 0.f);
  if (o < NOUT) v = *reinterpret_cast<const float4*>(&w[(size_t)o * D1 + j0 + 4 * tx]);
  tile[ty][4 * tx + 0] = v.x;
  tile[ty][4 * tx + 1] = v.y;
  tile[ty][4 * tx + 2] = v.z;
  tile[ty][4 * tx + 3] = v.w;
  __syncthreads();
  float4 u;
  u.x = tile[4 * tx + 0][ty];
  u.y = tile[4 * tx + 1][ty];
  u.z = tile[4 * tx + 2][ty];
  u.w = tile[4 * tx + 3][ty];
  *reinterpret_cast<float4*>(&wt[(size_t)(j0 + ty) * D1 + o0 + 4 * tx]) = u;
}

// ---------------------------------------------------------------------------
// Per-batch counting sort with 8-ALIGNED bucket starts (pad slots = 0 so a
// masked tail group gathers row 0 and masks it — no OOB, no serial tail).
// starts layout per batch: [0..33] aligned starts (34), [34..66] true lens.
// prep_sort0: key = rint(x[b][idx0[j]]*32) (compute_N0 fused).
// ---------------------------------------------------------------------------
__global__ void prep_sort0_k(const float* __restrict__ x, const int* __restrict__ idx0,
                             uint16_t* __restrict__ perm, int* __restrict__ starts) {
  __shared__ int keys[D0];
  __shared__ int hist[33];
  __shared__ int base[34];
  __shared__ int cursor[33];
  int b = blockIdx.x;
  int tid = threadIdx.x;
  if (tid < 33) hist[tid] = 0;
  for (int p = tid; p < PD0; p += 256) perm[(size_t)b * PD0 + p] = 0;
  __syncthreads();
  for (int j = tid; j < D0; j += 256) {
    int k = (int)rintf(x[b * D0 + idx0[j]] * 32.0f);
    keys[j] = k;
    atomicAdd(&hist[k], 1);
  }
  __syncthreads();
  if (tid == 0) {
    int s = 0;
    for (int k = 0; k < 33; ++k) {
      base[k] = s; cursor[k] = s;
      s = (s + hist[k] + 7) & ~7;        // 8-aligned next start
    }
    base[33] = s;
  }
  __syncthreads();
  if (tid < 34) starts[b * 68 + tid] = base[tid];
  if (tid < 33) starts[b * 68 + 34 + tid] = hist[tid];
  for (int j = tid; j < D0; j += 256) {
    int k = keys[j];
    int pos = atomicAdd(&cursor[k], 1);
    perm[(size_t)b * PD0 + pos] = (uint16_t)j;
  }
}

// prep_sort1: key from pooled spike counts (pool_encode fused).
__global__ void prep_sort1_k(const int* __restrict__ k0, const int* __restrict__ idx1,
                             const int* __restrict__ idx2,
                             uint16_t* __restrict__ perm, int* __restrict__ starts) {
  __shared__ int keys[D1];
  __shared__ int hist[33];
  __shared__ int base[34];
  __shared__ int cursor[33];
  int b = blockIdx.x;
  int tid = threadIdx.x;
  if (tid < 33) hist[tid] = 0;
  for (int p = tid; p < PD1; p += 256) perm[(size_t)b * PD1 + p] = 0;
  __syncthreads();
  for (int j = tid; j < D1; j += 256) {
    int q2 = idx2[j];
    int c = q2 >> 4;
    int h2 = (q2 >> 2) & 3;
    int w2 = q2 & 3;
    int cnt = 0;
#pragma unroll
    for (int dh = 0; dh < 2; ++dh)
#pragma unroll
      for (int dw = 0; dw < 2; ++dw) {
        int q = c * 64 + (2 * h2 + dh) * 8 + (2 * w2 + dw);
        cnt += k0[b * D0 + idx1[q]];
      }
    int k = (int)rintf((float)cnt * 0.25f);
    keys[j] = k;
    atomicAdd(&hist[k], 1);
  }
  __syncthreads();
  if (tid == 0) {
    int s = 0;
    for (int k = 0; k < 33; ++k) {
      base[k] = s; cursor[k] = s;
      s = (s + hist[k] + 7) & ~7;
    }
    base[33] = s;
  }
  __syncthreads();
  if (tid < 34) starts[b * 68 + tid] = base[tid];
  if (tid < 33) starts[b * 68 + 34 + tid] = hist[tid];
  for (int j = tid; j < D1; j += 256) {
    int k = keys[j];
    int pos = atomicAdd(&cursor[k], 1);
    perm[(size_t)b * PD1 + pos] = (uint16_t)j;
  }
}

// ---------------------------------------------------------------------------
// LIF core, bucket decomposition, fp64-exact.
//
// Round-9 evidence: occupancy lever worked (41->77%, 233->217us) but (a)
// WRITE_SIZE 1->42 MB = scratch spill in the scan (bs[8] + 24 CSE'd cshare
// values > 64-VGPR cap), (b) FETCH 277 MB = 4.3x ideal because the 256-col
// slice (4 MB) exactly fills the per-XCD L2 — zero slack.
//
// Round-10 structure:
//  * 128-col tiles via gridDim.z (grid (8,NB,4)): per-XCD working set 2 MB =
//    half of L2 -> slack for perm/cnt/transition traffic.  blockIdx.x still
//    pins the XCD (linear id = x + 8*(y + 64*z), x fastest).
//  * 8 groups x 4 buckets (k = 8i+g+1): per-thread bs[4] = 8 VGPRs.
//  * Spill-free scan: ALL groups publish bs[4] to cshare[32][128]; group 0
//    scans reading LDS directly — bs is dead before the scan, no register
//    working set above the cap, no scratch.
// Inner loop unchanged (depth-2 gather pipeline, ds_read_b128 index quads,
// masked aligned tails on zero-padded buckets).
// ---------------------------------------------------------------------------
template <int D, int PD, int OSTRIDE>
__launch_bounds__(1024, 8)
__global__ void lif_core_k(const float* __restrict__ wt, const uint16_t* __restrict__ perm,
                           const int* __restrict__ starts, const float* __restrict__ thr_p,
                           int* __restrict__ cnt_out) {
  __shared__ double cshare[32][128];   // 32 KB: all groups publish bs[4]
  __shared__ uint16_t permS[PD];
  int tid = threadIdx.x;
  int b = blockIdx.y;
  int col = tid & 127;
  int g = __builtin_amdgcn_readfirstlane(tid >> 7);   // group 0..7, wave-uniform

  // Stage this batch's (aligned, zero-padded) perm into LDS.
  {
    const ushort2* p2 = reinterpret_cast<const ushort2*>(perm + (size_t)b * PD);
    ushort2* s2 = reinterpret_cast<ushort2*>(permS);
    for (int i = tid; i < PD / 2; i += 1024) s2[i] = p2[i];
  }
  __syncthreads();

  const int* stA = starts + b * 68;        // aligned starts[34]
  const int* stL = starts + b * 68 + 34;   // true lens[33]
  double th = (double)thr_p[0];
  int o = (blockIdx.x + gridDim.x * blockIdx.z) * 128 + col;

#define RDIDX(P) do { \
    const uint32_t* _q = reinterpret_cast<const uint32_t*>(permS + ip); \
    uint32_t _w0 = _q[0], _w1 = _q[1], _w2 = _q[2], _w3 = _q[3]; \
    uint32_t _s0 = __builtin_amdgcn_readfirstlane(_w0); \
    uint32_t _s1 = __builtin_amdgcn_readfirstlane(_w1); \
    uint32_t _s2 = __builtin_amdgcn_readfirstlane(_w2); \
    uint32_t _s3 = __builtin_amdgcn_readfirstlane(_w3); \
    P##0 = _s0 & 0xffffu; P##1 = _s0 >> 16; \
    P##2 = _s1 & 0xffffu; P##3 = _s1 >> 16; \
    P##4 = _s2 & 0xffffu; P##5 = _s2 >> 16; \
    P##6 = _s3 & 0xffffu; P##7 = _s3 >> 16; \
    ip += 8; \
  } while (0)

#define GATHER(F, P) do { \
    F##0 = wt[(size_t)P##0 * OSTRIDE + o]; \
    F##1 = wt[(size_t)P##1 * OSTRIDE + o]; \
    F##2 = wt[(size_t)P##2 * OSTRIDE + o]; \
    F##3 = wt[(size_t)P##3 * OSTRIDE + o]; \
    F##4 = wt[(size_t)P##4 * OSTRIDE + o]; \
    F##5 = wt[(size_t)P##5 * OSTRIDE + o]; \
    F##6 = wt[(size_t)P##6 * OSTRIDE + o]; \
    F##7 = wt[(size_t)P##7 * OSTRIDE + o]; \
  } while (0)

#define ACC8(F) do { \
    a0 += (double)F##0; a1 += (double)F##1; a2 += (double)F##2; a3 += (double)F##3; \
    a0 += (double)F##4; a1 += (double)F##5; a2 += (double)F##6; a3 += (double)F##7; \
  } while (0)

  double bs[4];
#pragma unroll
  for (int i = 0; i < 4; ++i) bs[i] = 0.0;

#pragma unroll
  for (int i = 0; i < 4; ++i) {
    int k = 8 * i + g + 1;             // this group's i-th bucket (1..32)
    int hs0 = __builtin_amdgcn_readfirstlane(stA[k]);
    int len = __builtin_amdgcn_readfirstlane(stL[k]);
    if (len == 0) continue;            // scalar branch
    int ip = hs0;
    int ng = len >> 3, rem = len & 7;
    uint32_t pA0, pA1, pA2, pA3, pA4, pA5, pA6, pA7;
    uint32_t pB0, pB1, pB2, pB3, pB4, pB5, pB6, pB7;
    float fA0, fA1, fA2, fA3, fA4, fA5, fA6, fA7;
    float fB0, fB1, fB2, fB3, fB4, fB5, fB6, fB7;
    double a0 = 0.0, a1 = 0.0, a2 = 0.0, a3 = 0.0;
    if (ng > 0) {
      RDIDX(pA); GATHER(fA, pA);
      int gg = 1;
      for (; gg + 1 < ng; gg += 2) {
        RDIDX(pB); GATHER(fB, pB);     // next group in flight...
        ACC8(fA);                      // ...while this one accumulates
        RDIDX(pA); GATHER(fA, pA);
        ACC8(fB);
      }
      if (gg < ng) {
        RDIDX(pB); GATHER(fB, pB);
        ACC8(fA);
        ACC8(fB);
      } else {
        ACC8(fA);
      }
    }
    if (rem) {                         // aligned masked tail (pad reads row 0)
      RDIDX(pA); GATHER(fA, pA);
      a0 += (double)fA0;               // rem >= 1 always here
      if (rem > 1) a1 += (double)fA1;
      if (rem > 2) a2 += (double)fA2;
      if (rem > 3) a3 += (double)fA3;
      if (rem > 4) a0 += (double)fA4;
      if (rem > 5) a1 += (double)fA5;
      if (rem > 6) a2 += (double)fA6;
    }
    bs[i] = (a0 + a1) + (a2 + a3);
  }

  // All groups publish (bucket k -> row ((k-1)&7)*4 + ((k-1)>>3) = g*4+i).
#pragma unroll
  for (int i = 0; i < 4; ++i) cshare[g * 4 + i][col] = bs[i];
  __syncthreads();

  if (g == 0) {
    // Membrane scan: 528 compile-time-selected fp64 adds, terms read from
    // LDS (bs is dead -> no register pressure above the 64-VGPR cap).
    double memb = 0.0;
    int cnt = 0;
#pragma unroll
    for (int t = 0; t < 32; ++t) {
#pragma unroll
      for (int k = 1; k <= 32; ++k)
        if ((spike_pattern_ct(k) >> t) & 1u) {
          const int row = ((k - 1) & 7) * 4 + ((k - 1) >> 3);
          memb += cshare[row][col];
        }
      if (memb > th) { memb -= th; ++cnt; }   // strict: threshold < memb
    }
    cnt_out[(size_t)b * OSTRIDE + o] = cnt;
  }

#undef RDIDX
#undef GATHER
#undef ACC8
}

__global__ void write_out_k(const int* __restrict__ cnt2, const int* __restrict__ idx_out,
                            float* __restrict__ out) {
  int i = blockIdx.x * 256 + threadIdx.x;
  if (i >= NB * NOUT) return;
  int b = i / NOUT;
  int r = i - b * NOUT;
  out[i] = (float)cnt2[b * D1 + idx_out[r]];
}

// ---------------------------------------------------------------------------
extern "C" void kernel_launch(void* const* d_in, const int* in_sizes, int n_in,
                              void* d_out, int out_size, void* d_ws, size_t ws_size,
                              hipStream_t stream) {
  const float* x      = (const float*)d_in[0];
  const float* w0     = (const float*)d_in[1];
  const float* t0     = (const float*)d_in[2];
  const float* w2     = (const float*)d_in[3];
  const float* t2     = (const float*)d_in[4];
  const int*   idx0   = (const int*)d_in[5];
  const int*   idx1   = (const int*)d_in[6];
  const int*   idx2   = (const int*)d_in[7];
  const int*   idx_out= (const int*)d_in[8];
  float* out = (float*)d_out;

  char* ws = (char*)d_ws;
  float*    w0T    = (float*)ws;    ws += (size_t)D0 * D0 * 4;   // 64 MB
  float*    w2T    = (float*)ws;    ws += (size_t)D1 * D1 * 4;   // 4 MB
  uint16_t* perm0  = (uint16_t*)ws; ws += (size_t)NB * PD0 * 2;
  uint16_t* perm2  = (uint16_t*)ws; ws += (size_t)NB * PD1 * 2;
  int*      k0     = (int*)ws;      ws += (size_t)NB * D0 * 4;
  int*      cnt2   = (int*)ws;      ws += (size_t)NB * D1 * 4;
  int*      starts0= (int*)ws;      ws += (size_t)NB * 68 * 4;
  int*      starts2= (int*)ws;      ws += (size_t)NB * 68 * 4;

  transpose_w0_k<<<dim3(D0 / 32, D0 / 32), dim3(8, 32), 0, stream>>>(w0, w0T);
  transpose_w2_k<<<dim3(D1 / 32, D1 / 32), dim3(8, 32), 0, stream>>>(w2, w2T);
  prep_sort0_k<<<NB, 256, 0, stream>>>(x, idx0, perm0, starts0);
  // grid (8, NB, 4): 2048 blocks, 512 resident (2/CU, 32 waves/CU).  XCD x
  // streams 128-col (2 MB) slices z=0..3 sequentially — half-L2 working set.
  lif_core_k<D0, PD0, D0><<<dim3(8, NB, 4), 1024, 0, stream>>>(w0T, perm0, starts0, t0, k0);
  prep_sort1_k<<<NB, 256, 0, stream>>>(k0, idx1, idx2, perm2, starts2);
  lif_core_k<D1, PD1, D1><<<dim3(8, NB, 1), 1024, 0, stream>>>(w2T, perm2, starts2, t2, cnt2);
  write_out_k<<<(NB * NOUT + 255) / 256, 256, 0, stream>>>(cnt2, idx_out, out);
}